// Round 3
// baseline (683.665 us; speedup 1.0000x reference)
//
#include <hip/hip_runtime.h>
#include <math.h>

#define D_IN 16
#define D    64
#define H    128
#define EPSL 1e-5f
#define TN   64    // nodes per block (MLP kernels)

#define FOR4(M)  M(0) M(1) M(2) M(3)
#define FOR16(M) M(0) M(1) M(2) M(3) M(4) M(5) M(6) M(7) \
                 M(8) M(9) M(10) M(11) M(12) M(13) M(14) M(15)

// ---- 16-float LDS store / accumulate (b32, conflict-free at stride 65) ------
__device__ __forceinline__ void st16(float* p,
    const float4 a, const float4 b, const float4 c, const float4 d)
{
    p[0]=a.x;  p[1]=a.y;  p[2]=a.z;  p[3]=a.w;
    p[4]=b.x;  p[5]=b.y;  p[6]=b.z;  p[7]=b.w;
    p[8]=c.x;  p[9]=c.y;  p[10]=c.z; p[11]=c.w;
    p[12]=d.x; p[13]=d.y; p[14]=d.z; p[15]=d.w;
}
__device__ __forceinline__ void add16(float* p,
    const float4 a, const float4 b, const float4 c, const float4 d)
{
    p[0]+=a.x;  p[1]+=a.y;  p[2]+=a.z;  p[3]+=a.w;
    p[4]+=b.x;  p[5]+=b.y;  p[6]+=b.z;  p[7]+=b.w;
    p[8]+=c.x;  p[9]+=c.y;  p[10]+=c.z; p[11]+=c.w;
    p[12]+=d.x; p[13]+=d.y; p[14]+=d.z; p[15]+=d.w;
}

// ---------------- weight transpose (once per launch) ----------------
// w0t[j][k] = w0[k][j]   (64 x 16)
// wat[l][j2][k] = wa[l][k][j2]  (L x 128 x 64)
__global__ void k_transpose_w(const float* __restrict__ w0,
                              const float* __restrict__ wa,
                              float* __restrict__ w0t,
                              float* __restrict__ wat, int L)
{
    int i = blockIdx.x * blockDim.x + threadIdx.x;
    if (i < D * D_IN) {
        int j = i / D_IN, k = i % D_IN;
        w0t[i] = w0[k * D + j];
    }
    int tot = L * H * D;
    for (int t = i; t < tot; t += gridDim.x * blockDim.x) {
        int l  = t / (H * D);
        int r  = t % (H * D);
        int j2 = r / D, k = r % D;
        wat[l * H * D + j2 * D + k] = wa[l * D * H + k * H + j2];
    }
}

__global__ void k_zero(int* __restrict__ p, int n)
{
    int i = blockIdx.x * blockDim.x + threadIdx.x;
    if (i < n) p[i] = 0;
}

__global__ void k_hist(const int* __restrict__ dst, int* __restrict__ cnt, int E)
{
    int i = blockIdx.x * blockDim.x + threadIdx.x;
    if (i < E) atomicAdd(&cnt[dst[i]], 1);
}

// ---------------- hierarchical exclusive scan (3 kernels) ---------------------
__global__ void k_scan_blk(const int* __restrict__ cnt, int* __restrict__ off,
                           int* __restrict__ bsum, int N)
{
    __shared__ int sm[256];
    int t = threadIdx.x;
    int g = blockIdx.x * 256 + t;
    int v = (g < N) ? cnt[g] : 0;
    sm[t] = v;
    __syncthreads();
    for (int d2 = 1; d2 < 256; d2 <<= 1) {
        int u = (t >= d2) ? sm[t - d2] : 0;
        __syncthreads();
        sm[t] += u;
        __syncthreads();
    }
    if (g < N) off[g + 1] = sm[t];
    if (t == 255) bsum[blockIdx.x] = sm[255];
}

__global__ void k_scan_top(int* __restrict__ bsum, int G)
{
    __shared__ int sm[1024];
    int t = threadIdx.x;
    int v = (t < G) ? bsum[t] : 0;
    sm[t] = v;
    __syncthreads();
    for (int d2 = 1; d2 < 1024; d2 <<= 1) {
        int u = (t >= d2) ? sm[t - d2] : 0;
        __syncthreads();
        sm[t] += u;
        __syncthreads();
    }
    if (t < G) bsum[t] = sm[t] - v;   // exclusive
}

__global__ void k_scan_add(int* __restrict__ off, const int* __restrict__ bsum, int N)
{
    int g = blockIdx.x * 256 + threadIdx.x;
    if (g < N) off[g + 1] += bsum[blockIdx.x];
    if (g == 0) off[0] = 0;
}

__global__ void k_fill(const int* __restrict__ src, const int* __restrict__ dst,
                       const int* __restrict__ off, int* __restrict__ fill,
                       int* __restrict__ csr, int E)
{
    int i = blockIdx.x * blockDim.x + threadIdx.x;
    if (i < E) {
        int d = dst[i];
        int p = atomicAdd(&fill[d], 1);
        csr[off[d] + p] = src[i];
    }
}

// ---------------- per-layer MLP: m = mlp_silu_ln(h; wa,ba,wb,bb) --------------
// K-split: thread (split,nloc) keeps hid[split*32..+32) of its node in REGS
// (phase 1), then accumulates partials for ALL 64 output channels over those
// 32 hiddens (phase 2: 64 FMA per wave-uniform 256B s_load row, no ds_read).
// Cross-split reduce: 4-pass channel-quarter rotation in LDS. Then bias+SiLU+LN.
// launch_bounds(256,2): (256,4) made the allocator clamp to 64 VGPR and spill
// hv[32] to scratch (round-2 counters: +25MB WRITE_SIZE). Live set ~110 regs;
// <=128 still yields 4 waves/SIMD by the HW occupancy steps.
__global__ __launch_bounds__(256, 2) void k_mlp(const float* __restrict__ h,
                                                const float* __restrict__ wat,
                                                const float* __restrict__ ba,
                                                const float* __restrict__ wb,
                                                const float* __restrict__ bb,
                                                float* __restrict__ m, int N)
{
    __shared__ float buf[TN * 65];     // 16.25 KB channel-sum rotation buffer
    __shared__ float red_s[256];
    __shared__ float red_q[256];

    int tid   = threadIdx.x;
    int nloc  = tid & 63;
    int split = __builtin_amdgcn_readfirstlane(tid >> 6);   // wave id, uniform
    int node  = blockIdx.x * TN + nloc;
    int nc    = min(node, N - 1);

    const float4* hp = (const float4*)(h + (size_t)nc * D);
#define LOADH(i) float4 h##i = hp[i];
    FOR16(LOADH)
#undef LOADH

    // phase 1: hid[jj] for j2 = split*32 + jj, kept in registers
    float hv[32];
#pragma unroll
    for (int jj = 0; jj < 32; ++jj) {
        int j2 = split * 32 + jj;
        const float4* wr_ = (const float4*)(wat + j2 * D);
        float p0 = 0.f, p1 = 0.f, p2 = 0.f, p3 = 0.f;
#define DOT1(i) { float4 w_ = wr_[i]; \
        p0 = fmaf(h##i.x, w_.x, p0); p1 = fmaf(h##i.y, w_.y, p1); \
        p2 = fmaf(h##i.z, w_.z, p2); p3 = fmaf(h##i.w, w_.w, p3); }
        FOR16(DOT1)
#undef DOT1
        hv[jj] = fmaxf(ba[j2] + ((p0 + p1) + (p2 + p3)), 0.f);
    }

    // phase 2: partials for all 64 channels over my 32 hiddens
    float4 a0={0,0,0,0}, a1={0,0,0,0}, a2={0,0,0,0}, a3={0,0,0,0};
    float4 a4={0,0,0,0}, a5={0,0,0,0}, a6={0,0,0,0}, a7={0,0,0,0};
    float4 a8={0,0,0,0}, a9={0,0,0,0}, a10={0,0,0,0}, a11={0,0,0,0};
    float4 a12={0,0,0,0}, a13={0,0,0,0}, a14={0,0,0,0}, a15={0,0,0,0};
#pragma unroll
    for (int jj = 0; jj < 32; ++jj) {
        int j2 = split * 32 + jj;
        const float4* wo_ = (const float4*)(wb + j2 * D);
        float hd_ = hv[jj];
#define ACC1(i) { float4 w_ = wo_[i]; \
        a##i.x = fmaf(hd_, w_.x, a##i.x); a##i.y = fmaf(hd_, w_.y, a##i.y); \
        a##i.z = fmaf(hd_, w_.z, a##i.z); a##i.w = fmaf(hd_, w_.w, a##i.w); }
        FOR16(ACC1)
#undef ACC1
    }

    // cross-split reduce: rotation over channel quarters (disjoint per pass)
    float* bp = buf + nloc * 65;
#pragma unroll
    for (int p = 0; p < 4; ++p) {
        int q = (split + p) & 3;
        float* qp = bp + q * 16;
        if (p == 0) {
            switch (q) {
                case 0:  st16(qp, a0,  a1,  a2,  a3);  break;
                case 1:  st16(qp, a4,  a5,  a6,  a7);  break;
                case 2:  st16(qp, a8,  a9,  a10, a11); break;
                default: st16(qp, a12, a13, a14, a15); break;
            }
        } else {
            switch (q) {
                case 0:  add16(qp, a0,  a1,  a2,  a3);  break;
                case 1:  add16(qp, a4,  a5,  a6,  a7);  break;
                case 2:  add16(qp, a8,  a9,  a10, a11); break;
                default: add16(qp, a12, a13, a14, a15); break;
            }
        }
        __syncthreads();
    }

    // readback my 16 channels, + bias, SiLU
    float* rp = bp + split * 16;
    float4 o0, o1, o2, o3;
    o0.x=rp[0];  o0.y=rp[1];  o0.z=rp[2];  o0.w=rp[3];
    o1.x=rp[4];  o1.y=rp[5];  o1.z=rp[6];  o1.w=rp[7];
    o2.x=rp[8];  o2.y=rp[9];  o2.z=rp[10]; o2.w=rp[11];
    o3.x=rp[12]; o3.y=rp[13]; o3.z=rp[14]; o3.w=rp[15];
    const float4* bq = (const float4*)(bb + split * 16);
    float4 bv0=bq[0], bv1=bq[1], bv2=bq[2], bv3=bq[3];
    o0.x+=bv0.x; o0.y+=bv0.y; o0.z+=bv0.z; o0.w+=bv0.w;
    o1.x+=bv1.x; o1.y+=bv1.y; o1.z+=bv1.z; o1.w+=bv1.w;
    o2.x+=bv2.x; o2.y+=bv2.y; o2.z+=bv2.z; o2.w+=bv2.w;
    o3.x+=bv3.x; o3.y+=bv3.y; o3.z+=bv3.z; o3.w+=bv3.w;

#define SILU4(v) { v.x = v.x / (1.f + __expf(-v.x)); v.y = v.y / (1.f + __expf(-v.y)); \
                   v.z = v.z / (1.f + __expf(-v.z)); v.w = v.w / (1.f + __expf(-v.w)); }
    SILU4(o0) SILU4(o1) SILU4(o2) SILU4(o3)
#undef SILU4

    // LN across 64 channels: 4-way cross-wave reduce
    float s = (o0.x + o0.y + o0.z + o0.w) + (o1.x + o1.y + o1.z + o1.w)
            + (o2.x + o2.y + o2.z + o2.w) + (o3.x + o3.y + o3.z + o3.w);
    float qv = 0.f;
#define SQ4(v) qv = fmaf(v.x, v.x, fmaf(v.y, v.y, fmaf(v.z, v.z, fmaf(v.w, v.w, qv))));
    SQ4(o0) SQ4(o1) SQ4(o2) SQ4(o3)
#undef SQ4
    red_s[tid] = s;
    red_q[tid] = qv;
    __syncthreads();

    float ts = 0.f, tq = 0.f;
#pragma unroll
    for (int sp = 0; sp < 4; ++sp) {
        ts += red_s[sp * 64 + nloc];
        tq += red_q[sp * 64 + nloc];
    }
    float mu  = ts * (1.f / D);
    float var = tq * (1.f / D) - mu * mu;
    float inv = rsqrtf(var + EPSL);

    if (node < N) {
        float4* mp = (float4*)(m + (size_t)node * D + split * 16);
        float4 v;
        v.x = (o0.x - mu) * inv; v.y = (o0.y - mu) * inv;
        v.z = (o0.z - mu) * inv; v.w = (o0.w - mu) * inv; mp[0] = v;
        v.x = (o1.x - mu) * inv; v.y = (o1.y - mu) * inv;
        v.z = (o1.z - mu) * inv; v.w = (o1.w - mu) * inv; mp[1] = v;
        v.x = (o2.x - mu) * inv; v.y = (o2.y - mu) * inv;
        v.z = (o2.z - mu) * inv; v.w = (o2.w - mu) * inv; mp[2] = v;
        v.x = (o3.x - mu) * inv; v.y = (o3.y - mu) * inv;
        v.z = (o3.z - mu) * inv; v.w = (o3.w - mu) * inv; mp[3] = v;
    }
}

// ---------------- initial embedding: h = mlp_silu_ln(x; w0,b0,w1,b1) ----------
// same K-split structure; hidden dim 64 -> 16 hidden units per thread
__global__ __launch_bounds__(256, 2) void k_init(const float* __restrict__ x,
                                                 const float* __restrict__ w0t,
                                                 const float* __restrict__ b0,
                                                 const float* __restrict__ w1,
                                                 const float* __restrict__ b1,
                                                 float* __restrict__ h, int N)
{
    __shared__ float buf[TN * 65];
    __shared__ float red_s[256];
    __shared__ float red_q[256];

    int tid   = threadIdx.x;
    int nloc  = tid & 63;
    int split = __builtin_amdgcn_readfirstlane(tid >> 6);
    int node  = blockIdx.x * TN + nloc;
    int nc    = min(node, N - 1);

    const float4* xp = (const float4*)(x + (size_t)nc * D_IN);
#define LOADX(i) float4 x##i = xp[i];
    FOR4(LOADX)
#undef LOADX

    // phase 1: hid[jj] for j = split*16 + jj
    float hv[16];
#pragma unroll
    for (int jj = 0; jj < 16; ++jj) {
        int j = split * 16 + jj;
        const float4* wr_ = (const float4*)(w0t + j * D_IN);
        float p0 = 0.f, p1 = 0.f, p2 = 0.f, p3 = 0.f;
#define DOT1(i) { float4 w_ = wr_[i]; \
        p0 = fmaf(x##i.x, w_.x, p0); p1 = fmaf(x##i.y, w_.y, p1); \
        p2 = fmaf(x##i.z, w_.z, p2); p3 = fmaf(x##i.w, w_.w, p3); }
        FOR4(DOT1)
#undef DOT1
        hv[jj] = fmaxf(b0[j] + ((p0 + p1) + (p2 + p3)), 0.f);
    }

    // phase 2: partials for all 64 channels over my 16 hiddens
    float4 a0={0,0,0,0}, a1={0,0,0,0}, a2={0,0,0,0}, a3={0,0,0,0};
    float4 a4={0,0,0,0}, a5={0,0,0,0}, a6={0,0,0,0}, a7={0,0,0,0};
    float4 a8={0,0,0,0}, a9={0,0,0,0}, a10={0,0,0,0}, a11={0,0,0,0};
    float4 a12={0,0,0,0}, a13={0,0,0,0}, a14={0,0,0,0}, a15={0,0,0,0};
#pragma unroll
    for (int jj = 0; jj < 16; ++jj) {
        int j = split * 16 + jj;
        const float4* wo_ = (const float4*)(w1 + j * D);
        float hd_ = hv[jj];
#define ACC1(i) { float4 w_ = wo_[i]; \
        a##i.x = fmaf(hd_, w_.x, a##i.x); a##i.y = fmaf(hd_, w_.y, a##i.y); \
        a##i.z = fmaf(hd_, w_.z, a##i.z); a##i.w = fmaf(hd_, w_.w, a##i.w); }
        FOR16(ACC1)
#undef ACC1
    }

    float* bp = buf + nloc * 65;
#pragma unroll
    for (int p = 0; p < 4; ++p) {
        int q = (split + p) & 3;
        float* qp = bp + q * 16;
        if (p == 0) {
            switch (q) {
                case 0:  st16(qp, a0,  a1,  a2,  a3);  break;
                case 1:  st16(qp, a4,  a5,  a6,  a7);  break;
                case 2:  st16(qp, a8,  a9,  a10, a11); break;
                default: st16(qp, a12, a13, a14, a15); break;
            }
        } else {
            switch (q) {
                case 0:  add16(qp, a0,  a1,  a2,  a3);  break;
                case 1:  add16(qp, a4,  a5,  a6,  a7);  break;
                case 2:  add16(qp, a8,  a9,  a10, a11); break;
                default: add16(qp, a12, a13, a14, a15); break;
            }
        }
        __syncthreads();
    }

    float* rp = bp + split * 16;
    float4 o0, o1, o2, o3;
    o0.x=rp[0];  o0.y=rp[1];  o0.z=rp[2];  o0.w=rp[3];
    o1.x=rp[4];  o1.y=rp[5];  o1.z=rp[6];  o1.w=rp[7];
    o2.x=rp[8];  o2.y=rp[9];  o2.z=rp[10]; o2.w=rp[11];
    o3.x=rp[12]; o3.y=rp[13]; o3.z=rp[14]; o3.w=rp[15];
    const float4* bq = (const float4*)(b1 + split * 16);
    float4 bv0=bq[0], bv1=bq[1], bv2=bq[2], bv3=bq[3];
    o0.x+=bv0.x; o0.y+=bv0.y; o0.z+=bv0.z; o0.w+=bv0.w;
    o1.x+=bv1.x; o1.y+=bv1.y; o1.z+=bv1.z; o1.w+=bv1.w;
    o2.x+=bv2.x; o2.y+=bv2.y; o2.z+=bv2.z; o2.w+=bv2.w;
    o3.x+=bv3.x; o3.y+=bv3.y; o3.z+=bv3.z; o3.w+=bv3.w;

#define SILU4(v) { v.x = v.x / (1.f + __expf(-v.x)); v.y = v.y / (1.f + __expf(-v.y)); \
                   v.z = v.z / (1.f + __expf(-v.z)); v.w = v.w / (1.f + __expf(-v.w)); }
    SILU4(o0) SILU4(o1) SILU4(o2) SILU4(o3)
#undef SILU4

    float s = (o0.x + o0.y + o0.z + o0.w) + (o1.x + o1.y + o1.z + o1.w)
            + (o2.x + o2.y + o2.z + o2.w) + (o3.x + o3.y + o3.z + o3.w);
    float qv = 0.f;
#define SQ4(v) qv = fmaf(v.x, v.x, fmaf(v.y, v.y, fmaf(v.z, v.z, fmaf(v.w, v.w, qv))));
    SQ4(o0) SQ4(o1) SQ4(o2) SQ4(o3)
#undef SQ4
    red_s[tid] = s;
    red_q[tid] = qv;
    __syncthreads();

    float ts = 0.f, tq = 0.f;
#pragma unroll
    for (int sp = 0; sp < 4; ++sp) {
        ts += red_s[sp * 64 + nloc];
        tq += red_q[sp * 64 + nloc];
    }
    float mu  = ts * (1.f / D);
    float var = tq * (1.f / D) - mu * mu;
    float inv = rsqrtf(var + EPSL);

    if (node < N) {
        float4* hp2 = (float4*)(h + (size_t)node * D + split * 16);
        float4 v;
        v.x = (o0.x - mu) * inv; v.y = (o0.y - mu) * inv;
        v.z = (o0.z - mu) * inv; v.w = (o0.w - mu) * inv; hp2[0] = v;
        v.x = (o1.x - mu) * inv; v.y = (o1.y - mu) * inv;
        v.z = (o1.z - mu) * inv; v.w = (o1.w - mu) * inv; hp2[1] = v;
        v.x = (o2.x - mu) * inv; v.y = (o2.y - mu) * inv;
        v.z = (o2.z - mu) * inv; v.w = (o2.w - mu) * inv; hp2[2] = v;
        v.x = (o3.x - mu) * inv; v.y = (o3.y - mu) * inv;
        v.z = (o3.z - mu) * inv; v.w = (o3.w - mu) * inv; hp2[3] = v;
    }
}

// ---------------- aggregation: h += segment_mean(m[src], dst) ------------------
__global__ __launch_bounds__(256) void k_agg(const float* __restrict__ m,
                                             const int* __restrict__ csr,
                                             const int* __restrict__ off,
                                             const int* __restrict__ cnt,
                                             float* __restrict__ h, int N)
{
    int g = threadIdx.x >> 4;
    int c = threadIdx.x & 15;
    int node = blockIdx.x * 16 + g;
    if (node >= N) return;

    int b  = off[node];
    int e2 = off[node + 1];
    float4 s = {0.f, 0.f, 0.f, 0.f};
    for (int e = b; e < e2; ++e) {
        int sn = csr[e];
        float4 v = ((const float4*)(m + (size_t)sn * D))[c];
        s.x += v.x; s.y += v.y; s.z += v.z; s.w += v.w;
    }
    float dnm = fmaxf((float)cnt[node], 1.f);
    float inv = 1.f / dnm;

    float4* hp = (float4*)(h + (size_t)node * D);
    float4 hv = hp[c];
    hv.x = fmaf(s.x, inv, hv.x);
    hv.y = fmaf(s.y, inv, hv.y);
    hv.z = fmaf(s.z, inv, hv.z);
    hv.w = fmaf(s.w, inv, hv.w);
    hp[c] = hv;
}

extern "C" void kernel_launch(void* const* d_in, const int* in_sizes, int n_in,
                              void* d_out, int out_size, void* d_ws, size_t ws_size,
                              hipStream_t stream)
{
    const float* x  = (const float*)d_in[0];
    const int*   ei = (const int*)d_in[1];
    const float* w0 = (const float*)d_in[2];
    const float* b0 = (const float*)d_in[3];
    const float* w1 = (const float*)d_in[4];
    const float* b1 = (const float*)d_in[5];
    const float* wa = (const float*)d_in[6];
    const float* ba = (const float*)d_in[7];
    const float* wb = (const float*)d_in[8];
    const float* bb = (const float*)d_in[9];

    const int N = in_sizes[0] / D_IN;
    const int E = in_sizes[1] / 2;
    const int L = in_sizes[6] / (D * H);

    const int* src = ei;
    const int* dst = ei + E;

    // workspace layout (256B aligned chunks)
    char* ws = (char*)d_ws;
    size_t o = 0;
    auto carve = [&](size_t bytes) -> char* {
        char* p = ws + o;
        o = (o + bytes + 255) & ~(size_t)255;
        return p;
    };
    float* m    = (float*)carve((size_t)N * D * sizeof(float));
    int*   csr  = (int*)  carve((size_t)E * sizeof(int));
    int*   cnt  = (int*)  carve((size_t)N * sizeof(int));
    int*   fill = (int*)  carve((size_t)N * sizeof(int));
    int*   offp = (int*)  carve((size_t)(N + 1) * sizeof(int));
    int*   bsum = (int*)  carve((size_t)1024 * sizeof(int));
    float* w0t  = (float*)carve((size_t)D * D_IN * sizeof(float));
    float* wat  = (float*)carve((size_t)L * H * D * sizeof(float));

    float* h = (float*)d_out;

    const int nb = (N + TN - 1) / TN;
    const int G1 = (N + 255) / 256;

    k_transpose_w<<<64, 256, 0, stream>>>(w0, wa, w0t, wat, L);
    k_zero<<<(N + 255) / 256, 256, 0, stream>>>(cnt, N);
    k_zero<<<(N + 255) / 256, 256, 0, stream>>>(fill, N);
    k_hist<<<(E + 255) / 256, 256, 0, stream>>>(dst, cnt, E);
    k_scan_blk<<<G1, 256, 0, stream>>>(cnt, offp, bsum, N);
    k_scan_top<<<1, 1024, 0, stream>>>(bsum, G1);
    k_scan_add<<<G1, 256, 0, stream>>>(offp, bsum, N);
    k_fill<<<(E + 255) / 256, 256, 0, stream>>>(src, dst, offp, fill, csr, E);

    k_init<<<nb, 256, 0, stream>>>(x, w0t, b0, w1, b1, h, N);

    for (int l = 0; l < L; ++l) {
        k_mlp<<<nb, 256, 0, stream>>>(h, wat + (size_t)l * H * D,
                                      ba + (size_t)l * H,
                                      wb + (size_t)l * H * D,
                                      bb + (size_t)l * D, m, N);
        k_agg<<<(N + 15) / 16, 256, 0, stream>>>(m, csr, offp, cnt, h, N);
    }
}

// Round 4
// 429.564 us; speedup vs baseline: 1.5915x; 1.5915x over previous
//
#include <hip/hip_runtime.h>
#include <math.h>

#define D_IN 16
#define D    64
#define H    128
#define EPSL 1e-5f

// =======================================================================
// Graph preprocessing (unchanged from round 2/3: hist + hierarchical scan
// + CSR fill). k_transpose_w is DELETED: the GEMM-tile MLP kernels consume
// w0/w1/wa/wb in their native row-major layouts.
// =======================================================================

__global__ void k_zero(int* __restrict__ p, int n)
{
    int i = blockIdx.x * blockDim.x + threadIdx.x;
    if (i < n) p[i] = 0;
}

__global__ void k_hist(const int* __restrict__ dst, int* __restrict__ cnt, int E)
{
    int i = blockIdx.x * blockDim.x + threadIdx.x;
    if (i < E) atomicAdd(&cnt[dst[i]], 1);
}

__global__ void k_scan_blk(const int* __restrict__ cnt, int* __restrict__ off,
                           int* __restrict__ bsum, int N)
{
    __shared__ int sm[256];
    int t = threadIdx.x;
    int g = blockIdx.x * 256 + t;
    int v = (g < N) ? cnt[g] : 0;
    sm[t] = v;
    __syncthreads();
    for (int d2 = 1; d2 < 256; d2 <<= 1) {
        int u = (t >= d2) ? sm[t - d2] : 0;
        __syncthreads();
        sm[t] += u;
        __syncthreads();
    }
    if (g < N) off[g + 1] = sm[t];
    if (t == 255) bsum[blockIdx.x] = sm[255];
}

__global__ void k_scan_top(int* __restrict__ bsum, int G)
{
    __shared__ int sm[1024];
    int t = threadIdx.x;
    int v = (t < G) ? bsum[t] : 0;
    sm[t] = v;
    __syncthreads();
    for (int d2 = 1; d2 < 1024; d2 <<= 1) {
        int u = (t >= d2) ? sm[t - d2] : 0;
        __syncthreads();
        sm[t] += u;
        __syncthreads();
    }
    if (t < G) bsum[t] = sm[t] - v;   // exclusive
}

__global__ void k_scan_add(int* __restrict__ off, const int* __restrict__ bsum, int N)
{
    int g = blockIdx.x * 256 + threadIdx.x;
    if (g < N) off[g + 1] += bsum[blockIdx.x];
    if (g == 0) off[0] = 0;
}

__global__ void k_fill(const int* __restrict__ src, const int* __restrict__ dst,
                       const int* __restrict__ off, int* __restrict__ fill,
                       int* __restrict__ csr, int E)
{
    int i = blockIdx.x * blockDim.x + threadIdx.x;
    if (i < E) {
        int d = dst[i];
        int p = atomicAdd(&fill[d], 1);
        csr[off[d] + p] = src[i];
    }
}

// =======================================================================
// GEMM-tiled MLP: m = LN(SiLU(relu(h*Wa + ba)*Wb + bb))
// 256 threads = 64 nodes/block. tidn = tid&15, tidc = tid>>4.
// Thread owns nodes {tidn + 16*i, i=0..3} (strided -> LDS accesses spread
// over 16 banks, <=2-way everywhere) and a per-lane CHANNEL group
// (tidc-dependent) -> weight loads are per-lane vector loads, never
// scalarized (rounds 0-3 were all latency-bound on uniform s_load chains).
// Phase 1: 4n x 8hc tile over k=64  (32 FMA : 2 VMEM : 4 ds_read per k)
// Phase 2: 4n x 4c  tile over k=128 (16 FMA : 1 VMEM : 4 ds_read per k)
// =======================================================================
__global__ __launch_bounds__(256) void k_mlp(const float* __restrict__ h,
                                             const float* __restrict__ wa,  // [64][128] native
                                             const float* __restrict__ ba,  // [128]
                                             const float* __restrict__ wb,  // [128][64] native
                                             const float* __restrict__ bb,  // [64]
                                             float* __restrict__ m, int N)
{
    __shared__ float h_s[64 * 65];      // staged h, stride 65
    __shared__ float hid_s[H * 65];     // hid transposed [hc][node], stride 65
    __shared__ float red_s[256];
    __shared__ float red_q[256];

    const int tid  = threadIdx.x;
    const int tidn = tid & 15;
    const int tidc = tid >> 4;          // 0..15
    const int wv   = tid >> 6;          // wave 0..3
    const int base = blockIdx.x * 64;

    // ---- stage h[64][64] -> h_s ----
    {
        int sn = tid & 63;
        int sc = tid >> 6;              // 16-col chunk per wave
        int gn = min(base + sn, N - 1);
        const float4* hp = (const float4*)(h + (size_t)gn * D + sc * 16);
        float4 a = hp[0], b = hp[1], c = hp[2], d = hp[3];
        float* r = h_s + sn * 65 + sc * 16;
        r[0]=a.x;  r[1]=a.y;  r[2]=a.z;  r[3]=a.w;
        r[4]=b.x;  r[5]=b.y;  r[6]=b.z;  r[7]=b.w;
        r[8]=c.x;  r[9]=c.y;  r[10]=c.z; r[11]=c.w;
        r[12]=d.x; r[13]=d.y; r[14]=d.z; r[15]=d.w;
    }
    __syncthreads();

    // ---- phase 1: hid[tidn+16i][8*tidc + c] ----
    float acc[4][8];
#pragma unroll
    for (int i = 0; i < 4; ++i)
#pragma unroll
        for (int c = 0; c < 8; ++c) acc[i][c] = 0.f;

#pragma unroll 4
    for (int k = 0; k < D; ++k) {
        float4 w0v = *(const float4*)(wa + k * H + tidc * 8);
        float4 w1v = *(const float4*)(wa + k * H + tidc * 8 + 4);
        float hv0 = h_s[tidn * 65 + k];
        float hv1 = h_s[(tidn + 16) * 65 + k];
        float hv2 = h_s[(tidn + 32) * 65 + k];
        float hv3 = h_s[(tidn + 48) * 65 + k];
#define P1(i, hv) \
        acc[i][0]=fmaf(hv,w0v.x,acc[i][0]); acc[i][1]=fmaf(hv,w0v.y,acc[i][1]); \
        acc[i][2]=fmaf(hv,w0v.z,acc[i][2]); acc[i][3]=fmaf(hv,w0v.w,acc[i][3]); \
        acc[i][4]=fmaf(hv,w1v.x,acc[i][4]); acc[i][5]=fmaf(hv,w1v.y,acc[i][5]); \
        acc[i][6]=fmaf(hv,w1v.z,acc[i][6]); acc[i][7]=fmaf(hv,w1v.w,acc[i][7]);
        P1(0, hv0) P1(1, hv1) P1(2, hv2) P1(3, hv3)
#undef P1
    }

    {
        float4 ba0 = *(const float4*)(ba + tidc * 8);
        float4 ba1 = *(const float4*)(ba + tidc * 8 + 4);
        float bav[8] = {ba0.x, ba0.y, ba0.z, ba0.w, ba1.x, ba1.y, ba1.z, ba1.w};
#pragma unroll
        for (int c = 0; c < 8; ++c) {
            float* row = hid_s + (tidc * 8 + c) * 65 + tidn;
#pragma unroll
            for (int i = 0; i < 4; ++i)
                row[16 * i] = fmaxf(acc[i][c] + bav[c], 0.f);
        }
    }
    __syncthreads();

    // ---- phase 2: out[tidn+16i][4*tidc + j] over k=0..127 ----
    float o[4][4];
#pragma unroll
    for (int i = 0; i < 4; ++i)
#pragma unroll
        for (int j = 0; j < 4; ++j) o[i][j] = 0.f;

#pragma unroll 8
    for (int k = 0; k < H; ++k) {
        float4 wv4 = *(const float4*)(wb + k * D + tidc * 4);
        float d0 = hid_s[k * 65 + tidn];
        float d1 = hid_s[k * 65 + tidn + 16];
        float d2 = hid_s[k * 65 + tidn + 32];
        float d3 = hid_s[k * 65 + tidn + 48];
#define P2(i, dv) \
        o[i][0]=fmaf(dv,wv4.x,o[i][0]); o[i][1]=fmaf(dv,wv4.y,o[i][1]); \
        o[i][2]=fmaf(dv,wv4.z,o[i][2]); o[i][3]=fmaf(dv,wv4.w,o[i][3]);
        P2(0, d0) P2(1, d1) P2(2, d2) P2(3, d3)
#undef P2
    }

    // ---- bias + SiLU + per-node partial sums ----
    float4 bbv = *(const float4*)(bb + tidc * 4);
    float bz[4] = {bbv.x, bbv.y, bbv.z, bbv.w};
    float s[4], q[4];
#pragma unroll
    for (int i = 0; i < 4; ++i) {
        float ss = 0.f, qq = 0.f;
#pragma unroll
        for (int j = 0; j < 4; ++j) {
            float t = o[i][j] + bz[j];
            t = t / (1.f + __expf(-t));
            o[i][j] = t;
            ss += t;
            qq = fmaf(t, t, qq);
        }
        s[i] = ss; q[i] = qq;
    }

    // LN reduce: in-wave over tidc&3 (lanes ^16, ^32), cross-wave via LDS
#pragma unroll
    for (int i = 0; i < 4; ++i) {
        s[i] += __shfl_xor(s[i], 16, 64);
        s[i] += __shfl_xor(s[i], 32, 64);
        q[i] += __shfl_xor(q[i], 16, 64);
        q[i] += __shfl_xor(q[i], 32, 64);
    }
    if ((tidc & 3) == 0) {
#pragma unroll
        for (int i = 0; i < 4; ++i) {
            red_s[wv * 64 + i * 16 + tidn] = s[i];
            red_q[wv * 64 + i * 16 + tidn] = q[i];
        }
    }
    __syncthreads();

#pragma unroll
    for (int i = 0; i < 4; ++i) {
        int r = i * 16 + tidn;
        float ts = red_s[r] + red_s[64 + r] + red_s[128 + r] + red_s[192 + r];
        float tq = red_q[r] + red_q[64 + r] + red_q[128 + r] + red_q[192 + r];
        float mu  = ts * (1.f / D);
        float var = tq * (1.f / D) - mu * mu;
        float inv = rsqrtf(var + EPSL);
        int node = base + tidn + 16 * i;
        if (node < N) {
            float4 outv;
            outv.x = (o[i][0] - mu) * inv;
            outv.y = (o[i][1] - mu) * inv;
            outv.z = (o[i][2] - mu) * inv;
            outv.w = (o[i][3] - mu) * inv;
            *(float4*)(m + (size_t)node * D + tidc * 4) = outv;
        }
    }
}

// =======================================================================
// Initial embedding, same GEMM-tile structure.
// Phase 1: 4n x 4hc over k=16 (w0 [16][64] native)
// Phase 2: 4n x 4c  over k=64 (w1 [64][64] native)
// =======================================================================
__global__ __launch_bounds__(256) void k_init(const float* __restrict__ x,
                                              const float* __restrict__ w0,
                                              const float* __restrict__ b0,
                                              const float* __restrict__ w1,
                                              const float* __restrict__ b1,
                                              float* __restrict__ h, int N)
{
    __shared__ float x_s[64 * 17];
    __shared__ float hid_s[D * 65];
    __shared__ float red_s[256];
    __shared__ float red_q[256];

    const int tid  = threadIdx.x;
    const int tidn = tid & 15;
    const int tidc = tid >> 4;
    const int wv   = tid >> 6;
    const int base = blockIdx.x * 64;

    // stage x[64][16]
    {
        int sn = tid & 63;
        int sc = tid >> 6;              // 4-col chunk
        int gn = min(base + sn, N - 1);
        float4 xv = *(const float4*)(x + (size_t)gn * D_IN + sc * 4);
        float* r = x_s + sn * 17 + sc * 4;
        r[0] = xv.x; r[1] = xv.y; r[2] = xv.z; r[3] = xv.w;
    }
    __syncthreads();

    // phase 1: hid[tidn+16i][4*tidc + c], k = 0..15
    float a1[4][4];
#pragma unroll
    for (int i = 0; i < 4; ++i)
#pragma unroll
        for (int c = 0; c < 4; ++c) a1[i][c] = 0.f;

#pragma unroll
    for (int k = 0; k < D_IN; ++k) {
        float4 wv4 = *(const float4*)(w0 + k * D + tidc * 4);
        float x0 = x_s[tidn * 17 + k];
        float x1 = x_s[(tidn + 16) * 17 + k];
        float x2 = x_s[(tidn + 32) * 17 + k];
        float x3 = x_s[(tidn + 48) * 17 + k];
#define Q1(i, xv) \
        a1[i][0]=fmaf(xv,wv4.x,a1[i][0]); a1[i][1]=fmaf(xv,wv4.y,a1[i][1]); \
        a1[i][2]=fmaf(xv,wv4.z,a1[i][2]); a1[i][3]=fmaf(xv,wv4.w,a1[i][3]);
        Q1(0, x0) Q1(1, x1) Q1(2, x2) Q1(3, x3)
#undef Q1
    }

    {
        float4 b0v = *(const float4*)(b0 + tidc * 4);
        float bz0[4] = {b0v.x, b0v.y, b0v.z, b0v.w};
#pragma unroll
        for (int c = 0; c < 4; ++c) {
            float* row = hid_s + (tidc * 4 + c) * 65 + tidn;
#pragma unroll
            for (int i = 0; i < 4; ++i)
                row[16 * i] = fmaxf(a1[i][c] + bz0[c], 0.f);
        }
    }
    __syncthreads();

    // phase 2: out over k = 0..63
    float o[4][4];
#pragma unroll
    for (int i = 0; i < 4; ++i)
#pragma unroll
        for (int j = 0; j < 4; ++j) o[i][j] = 0.f;

#pragma unroll 8
    for (int k = 0; k < D; ++k) {
        float4 wv4 = *(const float4*)(w1 + k * D + tidc * 4);
        float d0 = hid_s[k * 65 + tidn];
        float d1 = hid_s[k * 65 + tidn + 16];
        float d2 = hid_s[k * 65 + tidn + 32];
        float d3 = hid_s[k * 65 + tidn + 48];
#define P2(i, dv) \
        o[i][0]=fmaf(dv,wv4.x,o[i][0]); o[i][1]=fmaf(dv,wv4.y,o[i][1]); \
        o[i][2]=fmaf(dv,wv4.z,o[i][2]); o[i][3]=fmaf(dv,wv4.w,o[i][3]);
        P2(0, d0) P2(1, d1) P2(2, d2) P2(3, d3)
#undef P2
    }

    float4 bbv = *(const float4*)(b1 + tidc * 4);
    float bz[4] = {bbv.x, bbv.y, bbv.z, bbv.w};
    float s[4], q[4];
#pragma unroll
    for (int i = 0; i < 4; ++i) {
        float ss = 0.f, qq = 0.f;
#pragma unroll
        for (int j = 0; j < 4; ++j) {
            float t = o[i][j] + bz[j];
            t = t / (1.f + __expf(-t));
            o[i][j] = t;
            ss += t;
            qq = fmaf(t, t, qq);
        }
        s[i] = ss; q[i] = qq;
    }
#pragma unroll
    for (int i = 0; i < 4; ++i) {
        s[i] += __shfl_xor(s[i], 16, 64);
        s[i] += __shfl_xor(s[i], 32, 64);
        q[i] += __shfl_xor(q[i], 16, 64);
        q[i] += __shfl_xor(q[i], 32, 64);
    }
    if ((tidc & 3) == 0) {
#pragma unroll
        for (int i = 0; i < 4; ++i) {
            red_s[wv * 64 + i * 16 + tidn] = s[i];
            red_q[wv * 64 + i * 16 + tidn] = q[i];
        }
    }
    __syncthreads();

#pragma unroll
    for (int i = 0; i < 4; ++i) {
        int r = i * 16 + tidn;
        float ts = red_s[r] + red_s[64 + r] + red_s[128 + r] + red_s[192 + r];
        float tq = red_q[r] + red_q[64 + r] + red_q[128 + r] + red_q[192 + r];
        float mu  = ts * (1.f / D);
        float var = tq * (1.f / D) - mu * mu;
        float inv = rsqrtf(var + EPSL);
        int node = base + tidn + 16 * i;
        if (node < N) {
            float4 outv;
            outv.x = (o[i][0] - mu) * inv;
            outv.y = (o[i][1] - mu) * inv;
            outv.z = (o[i][2] - mu) * inv;
            outv.w = (o[i][3] - mu) * inv;
            *(float4*)(h + (size_t)node * D + tidc * 4) = outv;
        }
    }
}

// ---------------- aggregation: h += segment_mean(m[src], dst) ------------------
__global__ __launch_bounds__(256) void k_agg(const float* __restrict__ m,
                                             const int* __restrict__ csr,
                                             const int* __restrict__ off,
                                             const int* __restrict__ cnt,
                                             float* __restrict__ h, int N)
{
    int g = threadIdx.x >> 4;
    int c = threadIdx.x & 15;
    int node = blockIdx.x * 16 + g;
    if (node >= N) return;

    int b  = off[node];
    int e2 = off[node + 1];
    float4 s = {0.f, 0.f, 0.f, 0.f};
    for (int e = b; e < e2; ++e) {
        int sn = csr[e];
        float4 v = ((const float4*)(m + (size_t)sn * D))[c];
        s.x += v.x; s.y += v.y; s.z += v.z; s.w += v.w;
    }
    float dnm = fmaxf((float)cnt[node], 1.f);
    float inv = 1.f / dnm;

    float4* hp = (float4*)(h + (size_t)node * D);
    float4 hv = hp[c];
    hv.x = fmaf(s.x, inv, hv.x);
    hv.y = fmaf(s.y, inv, hv.y);
    hv.z = fmaf(s.z, inv, hv.z);
    hv.w = fmaf(s.w, inv, hv.w);
    hp[c] = hv;
}

extern "C" void kernel_launch(void* const* d_in, const int* in_sizes, int n_in,
                              void* d_out, int out_size, void* d_ws, size_t ws_size,
                              hipStream_t stream)
{
    const float* x  = (const float*)d_in[0];
    const int*   ei = (const int*)d_in[1];
    const float* w0 = (const float*)d_in[2];
    const float* b0 = (const float*)d_in[3];
    const float* w1 = (const float*)d_in[4];
    const float* b1 = (const float*)d_in[5];
    const float* wa = (const float*)d_in[6];
    const float* ba = (const float*)d_in[7];
    const float* wb = (const float*)d_in[8];
    const float* bb = (const float*)d_in[9];

    const int N = in_sizes[0] / D_IN;
    const int E = in_sizes[1] / 2;
    const int L = in_sizes[6] / (D * H);

    const int* src = ei;
    const int* dst = ei + E;

    // workspace layout (256B aligned chunks)
    char* ws = (char*)d_ws;
    size_t o = 0;
    auto carve = [&](size_t bytes) -> char* {
        char* p = ws + o;
        o = (o + bytes + 255) & ~(size_t)255;
        return p;
    };
    float* m    = (float*)carve((size_t)N * D * sizeof(float));
    int*   csr  = (int*)  carve((size_t)E * sizeof(int));
    int*   cnt  = (int*)  carve((size_t)N * sizeof(int));
    int*   fill = (int*)  carve((size_t)N * sizeof(int));
    int*   offp = (int*)  carve((size_t)(N + 1) * sizeof(int));
    int*   bsum = (int*)  carve((size_t)1024 * sizeof(int));

    float* h = (float*)d_out;

    const int nb = (N + 63) / 64;
    const int G1 = (N + 255) / 256;

    k_zero<<<(N + 255) / 256, 256, 0, stream>>>(cnt, N);
    k_zero<<<(N + 255) / 256, 256, 0, stream>>>(fill, N);
    k_hist<<<(E + 255) / 256, 256, 0, stream>>>(dst, cnt, E);
    k_scan_blk<<<G1, 256, 0, stream>>>(cnt, offp, bsum, N);
    k_scan_top<<<1, 1024, 0, stream>>>(bsum, G1);
    k_scan_add<<<G1, 256, 0, stream>>>(offp, bsum, N);
    k_fill<<<(E + 255) / 256, 256, 0, stream>>>(src, dst, offp, fill, csr, E);

    k_init<<<nb, 256, 0, stream>>>(x, w0, b0, w1, b1, h, N);

    for (int l = 0; l < L; ++l) {
        k_mlp<<<nb, 256, 0, stream>>>(h, wa + (size_t)l * D * H,
                                      ba + (size_t)l * H,
                                      wb + (size_t)l * H * D,
                                      bb + (size_t)l * D, m, N);
        k_agg<<<(N + 15) / 16, 256, 0, stream>>>(m, csr, offp, cnt, h, N);
    }
}